// Round 1
// baseline (109.672 us; speedup 1.0000x reference)
//
#include <hip/hip_runtime.h>
#include <math.h>

// Reference collapses analytically:
//   The per-step tridiagonal Thomas scan cp <- OFF/(DM - OFF*cp) with
//   OFF=1/h^2, DM=-2/h^2 is cp <- 1/(-2-cp), a Mobius map. With
//   cp_k = -d_{k-1}/d_k, d_k = k*cp0+k+1, the prod over 254 iters
//   telescopes to 1/(254*cp0+255). With cp0 = -255R/(255R+1):
//     j = 255*BC*(1+cp0)/(254*cp0+255) = BC/(R+1).
//   So each step is O(1); whole problem = 500-step scalar recurrence
//   per batch element, 256 independent elements.

#define BATCH  256
#define NSTEPS 500
#define NOUT   251   // 1 leading zero + 250 recorded steps (every 2nd)

__global__ __launch_bounds__(64) void film_growth_kernel(
    const float* __restrict__ z, float* __restrict__ out)
{
#pragma clang fp contract(off)
    int b = blockIdx.x * 64 + threadIdx.x;
    if (b >= BATCH) return;

    const float z0 = z[3 * b + 0];
    const float K  = z[3 * b + 1];
    const float jm = z[3 * b + 2];

    const float DT   = 0.5f;
    const float VRDT = 0.1f * 0.5f;   // VR*DT = 0.05f (bit-exact vs py double->f32)

    const float Cv = powf(10.0f, -z0);
    float Q = 0.0f, h = 0.0f, R = 1.0f, Qmin = 1e10f;

    float* o = out + (size_t)b * NOUT;
    o[0] = 0.0f;

    for (int i = 1; i <= NSTEPS; ++i) {
        const float BC = VRDT * (float)i;
        // closed-form telescoped Thomas solve
        const float j = BC / (R + 1.0f);

        if (i == 1) {
            const float beta = j / DT;
            Qmin = powf(81.0f / (128.0f * beta), 1.0f / 3.0f)
                 * powf(K, 4.0f / 3.0f);
        }

        const float Qn = Q + j * DT;

        // stable sigmoid(1e8*(Qn - Qmin)), matching jax.nn.sigmoid
        const float x = 1e8f * (Qn - Qmin);
        float w;
        if (x >= 0.0f) {
            w = 1.0f / (1.0f + expf(-x));
        } else {
            const float e = expf(x);
            w = e / (1.0f + e);
        }

        const float dh = Cv * (j - jm) * DT;
        const float hn = w * fmaxf(h + dh, 0.0f) + (1.0f - w) * h;

        const float rho = w * fmaxf(8.0e6f * expf(-0.1f * j), 2.0e6f);
        const float dR  = rho * (j - jm) * Cv * DT;
        const float Rn  = w * fmaxf(R + dR, 0.0f) + (1.0f - w) * R;

        Q = Qn; h = hn; R = Rn;

        if ((i & 1) == 0) o[i >> 1] = h;   // record i=2,4,...,500 -> t=1..250
    }
}

extern "C" void kernel_launch(void* const* d_in, const int* in_sizes, int n_in,
                              void* d_out, int out_size, void* d_ws, size_t ws_size,
                              hipStream_t stream) {
    const float* z   = (const float*)d_in[0];
    float*       out = (float*)d_out;
    film_growth_kernel<<<dim3((BATCH + 63) / 64), dim3(64), 0, stream>>>(z, out);
}

// Round 2
// 36.699 us; speedup vs baseline: 2.9885x; 2.9885x over previous
//
#include <hip/hip_runtime.h>
#include <math.h>

// Closed-form Thomas solve (telescoped Mobius recurrence): j = BC/(R+1).
// Sigmoid(1e8*(Qn-Qmin)) is saturated to float-exact {0,1} except on a
// ~3e-5-probability window (arg moves >=1.25e6/step) -> step select.
// rcp+1NR (~1ulp) and v_exp_f32 (~2ulp) sit below the ~1e-6 closed-form-vs-
// f32-scan difference that dominates the (passing) absmax.

#define BATCH  256
#define NSTEPS 500
#define NOUT   251   // 1 leading zero + 250 recorded steps (every 2nd)

__global__ __launch_bounds__(64) void film_growth_kernel(
    const float* __restrict__ z, float* __restrict__ out)
{
#pragma clang fp contract(off)
    int b = blockIdx.x * 64 + threadIdx.x;
    if (b >= BATCH) return;

    const float z0 = z[3 * b + 0];
    const float K  = z[3 * b + 1];
    const float jm = z[3 * b + 2];

    const float DT   = 0.5f;
    const float VRDT = 0.05f;          // 0.1f*0.5f exact

    const float Cv = powf(10.0f, -z0);

    // Hoisted i==1 Qmin: j1 = 0.05/(1+1) = 0.025 exact -> beta = 0.05 exact.
    const float beta = 0.05f;
    const float Qmin = powf(81.0f / (128.0f * beta), 1.0f / 3.0f)
                     * powf(K, 4.0f / 3.0f);

    float Q = 0.0f, h = 0.0f, R = 1.0f;

    float* o = out + (size_t)b * NOUT;
    o[0] = 0.0f;

    const float C_EXP = -0.14426950408889634f;  // -0.1 * log2(e)

    #pragma unroll 2
    for (int i = 1; i <= NSTEPS; ++i) {
        const float BC = VRDT * (float)i;

        // j = BC / (R+1) via hardware rcp + one Newton step (fma form)
        const float t = R + 1.0f;
        float r = __builtin_amdgcn_rcpf(t);
        r = fmaf(fmaf(-t, r, 1.0f), r, r);
        const float j = BC * r;

        const float Qn = Q + j * DT;
        const bool  w  = (Qn >= Qmin);   // step sigmoid (saturated regime)

        const float s  = j - jm;
        const float dh = (Cv * s) * DT;               // ref assoc: ((Cv*s)*DT)
        const float hn = w ? fmaxf(h + dh, 0.0f) : h;

        // rho = max(8e6*exp(-0.1*j), 2e6) via v_exp_f32: 2^(j * -0.1*log2e)
        const float em  = __builtin_amdgcn_exp2f(C_EXP * j);
        const float rho = fmaxf(8.0e6f * em, 2.0e6f);
        const float dR  = ((rho * s) * Cv) * DT;      // ref assoc
        const float Rn  = w ? fmaxf(R + dR, 0.0f) : R;

        Q = Qn; h = hn; R = Rn;

        if ((i & 1) == 0) o[i >> 1] = h;  // record i=2,4,...,500
    }
}

extern "C" void kernel_launch(void* const* d_in, const int* in_sizes, int n_in,
                              void* d_out, int out_size, void* d_ws, size_t ws_size,
                              hipStream_t stream) {
    const float* z   = (const float*)d_in[0];
    float*       out = (float*)d_out;
    film_growth_kernel<<<dim3((BATCH + 63) / 64), dim3(64), 0, stream>>>(z, out);
}

// Round 3
// 34.559 us; speedup vs baseline: 3.1734x; 1.0619x over previous
//
#include <hip/hip_runtime.h>
#include <math.h>

// Closed-form Thomas solve (telescoped Mobius recurrence): j = BC/(R+1).
// Latency-bound serial chain: 500 dependent iterations, 256 independent
// lanes (4 wave64). Optimization = shortening the per-iter dependence chain.
//
// Phase split: w = (Q >= Qmin) is monotone (Q strictly increasing, Qmin
// const); all lanes switch by i ~ sqrt(160*Qmin) <= ~20. Phase B drops
// Q, the compare, and both selects from the chain.
//
// All arithmetic rewrites are <=1ulp vs reference order, below the ~1e-6
// systematic closed-form-vs-scan offset (absmax bit-stable across rounds).

#define BATCH  256
#define NSTEPS 500
#define NOUT   251   // 1 leading zero + 250 recorded steps (every 2nd)

__global__ __launch_bounds__(64) void film_growth_kernel(
    const float* __restrict__ z, float* __restrict__ out)
{
#pragma clang fp contract(off)
    int b = blockIdx.x * 64 + threadIdx.x;
    if (b >= BATCH) return;

    const float z0 = z[3 * b + 0];
    const float K  = z[3 * b + 1];
    const float jm = z[3 * b + 2];

    const float VRDT = 0.05f;                  // VR*DT exact
    const float Cv   = powf(10.0f, -z0);
    const float CvDT = Cv * 0.5f;              // exact pow2 scale: (Cv*s)*DT == CvDT*s

    // i==1 hoist: j1 = 0.05/2 = 0.025 exact -> beta = 0.05 exact
    const float Qmin = powf(81.0f / (128.0f * 0.05f), 1.0f / 3.0f)
                     * powf(K, 4.0f / 3.0f);

    const float C_EXP = -0.14426950408889634f; // -0.1 * log2(e)
    const float L8E6  = 22.931568569324174f;   // log2(8e6)

    float Q = 0.0f, h = 0.0f, R = 1.0f;
    float* o = out + (size_t)b * NOUT;
    o[0] = 0.0f;

    int i = 1;
    // Phase A: until every lane in the wave has switched on
    for (; i <= NSTEPS; ++i) {
        const float BC   = VRDT * (float)i;    // off-chain per-i constants
        const float BCDT = BC * 0.5f;          // exact
        const float cBC  = C_EXP * BC;

        const float t = R + 1.0f;
        const float r = __builtin_amdgcn_rcpf(t);   // ~1ulp; j = BC*r implicit

        const float Qn = fmaf(BCDT, r, Q);     // Q + j*DT
        const bool  w  = (Qn >= Qmin);         // saturated sigmoid

        const float s   = fmaf(BC, r, -jm);    // j - jm
        const float rho = fmaxf(__builtin_amdgcn_exp2f(fmaf(cBC, r, L8E6)), 2.0e6f);

        const float hn = w ? fmaxf(fmaf(CvDT, s, h), 0.0f) : h;
        const float Rn = w ? fmaxf(fmaf(rho, s * CvDT, R), 0.0f) : R;

        Q = Qn; h = hn; R = Rn;
        if ((i & 1) == 0) o[i >> 1] = h;
        if (__all((int)w)) { ++i; break; }
    }

    // Phase B: w == 1 for all lanes forever; Q/compare/selects dropped
    #pragma unroll 2
    for (; i <= NSTEPS; ++i) {
        const float BC  = VRDT * (float)i;
        const float cBC = C_EXP * BC;

        const float t = R + 1.0f;
        const float r = __builtin_amdgcn_rcpf(t);

        const float s   = fmaf(BC, r, -jm);
        const float rho = fmaxf(__builtin_amdgcn_exp2f(fmaf(cBC, r, L8E6)), 2.0e6f);

        h = fmaxf(fmaf(CvDT, s, h), 0.0f);
        R = fmaxf(fmaf(rho, s * CvDT, R), 0.0f);

        if ((i & 1) == 0) o[i >> 1] = h;
    }
}

extern "C" void kernel_launch(void* const* d_in, const int* in_sizes, int n_in,
                              void* d_out, int out_size, void* d_ws, size_t ws_size,
                              hipStream_t stream) {
    const float* z   = (const float*)d_in[0];
    float*       out = (float*)d_out;
    film_growth_kernel<<<dim3((BATCH + 63) / 64), dim3(64), 0, stream>>>(z, out);
}

// Round 5
// 31.682 us; speedup vs baseline: 3.4616x; 1.0908x over previous
//
#include <hip/hip_runtime.h>
#include <math.h>

// Closed-form Thomas solve (telescoped Mobius recurrence): j = BC/(R+1).
// Latency-bound serial chain: 500 dependent iterations, 256 lanes (4 wave64).
//
// Dynamics: post-switch the system is a clamped relaxation oscillator
// (R jumps ~1e6, decays, clamps to exactly 0, repeats); the clamp resets
// state so ulp-level perturbations are tolerated (absmax bit-stable across
// arithmetic variants), but %-level rho perturbations flip decay-step counts
// and diverge (R4 lagged-rho failure, absmax 318). => rho stays SAME-STEP.
//
// Ulp-safe chain cuts vs the passing R3 kernel:
//  - state T = R+1: T' = max(fma(rho,s2,T),1)   (kills the pre-rcp add)
//  - s2 in one fma: s2 = fma(i*VRDT*CvDT, r, -jm*CvDT) = (j-jm)*Cv*DT
// Phase-B chain: rcp -> fma -> exp2 -> fmax -> fma -> fmax  (~40 cy).

#define BATCH  256
#define NSTEPS 500
#define NOUT   251   // 1 leading zero + 250 recorded steps (every 2nd)

__global__ __launch_bounds__(64) void film_growth_kernel(
    const float* __restrict__ z, float* __restrict__ out)
{
#pragma clang fp contract(off)
    int b = blockIdx.x * 64 + threadIdx.x;
    if (b >= BATCH) return;

    const float z0 = z[3 * b + 0];
    const float K  = z[3 * b + 1];
    const float jm = z[3 * b + 2];

    const float VRDT = 0.05f;                    // VR*DT exact
    const float Cv   = powf(10.0f, -z0);
    const float CvDT = Cv * 0.5f;                // exact pow2 scale
    const float stepCvDT = VRDT * CvDT;          // i*stepCvDT = BC_i*Cv*DT
    const float mjmCvDT  = -jm * CvDT;

    // i==1 hoist: j1 = 0.05/2 = 0.025 exact -> beta = 0.05 exact
    const float Qmin = powf(81.0f / (128.0f * 0.05f), 1.0f / 3.0f)
                     * powf(K, 4.0f / 3.0f);

    const float C_EXP  = -0.14426950408889634f;  // -0.1 * log2(e)
    const float C_EXPV = C_EXP * VRDT;           // exp-arg slope per i
    const float L8E6   = 22.931568569324174f;    // log2(8e6)

    float Q = 0.0f, h = 0.0f, T = 2.0f;          // T = R + 1

    float* o = out + (size_t)b * NOUT;
    o[0] = 0.0f;

    int i = 1;
    // ---- Phase A: until every lane in the wave has switched on ----
    for (; i <= NSTEPS; ++i) {
        const float fi = (float)i;

        const float r  = __builtin_amdgcn_rcpf(T);
        const float Qn = fmaf((VRDT * 0.5f) * fi, r, Q);     // Q + j*DT
        const bool  w  = (Qn >= Qmin);                       // saturated sigmoid

        const float s2  = fmaf(fi * stepCvDT, r, mjmCvDT);   // (j-jm)*Cv*DT
        const float rho = fmaxf(
            __builtin_amdgcn_exp2f(fmaf(C_EXPV * fi, r, L8E6)), 2.0e6f);

        const float hn = w ? fmaxf(h + s2, 0.0f) : h;
        const float Tn = w ? fmaxf(fmaf(rho, s2, T), 1.0f) : T;

        Q = Qn; h = hn; T = Tn;
        if ((i & 1) == 0) o[i >> 1] = h;
        if (__all((int)w)) { ++i; break; }
    }

    // ---- Phase B: w==1 forever; Q/compare/selects dropped; same-step rho ----
    #pragma unroll 2
    for (; i <= NSTEPS; ++i) {
        const float fi = (float)i;

        const float r   = __builtin_amdgcn_rcpf(T);          // T -> r
        const float s2  = fmaf(fi * stepCvDT, r, mjmCvDT);   // r -> s2
        const float rho = fmaxf(
            __builtin_amdgcn_exp2f(fmaf(C_EXPV * fi, r, L8E6)), 2.0e6f);

        T = fmaxf(fmaf(rho, s2, T), 1.0f);                   // rho,s2 -> T'
        h = fmaxf(h + s2, 0.0f);                             // parallel chain

        if ((i & 1) == 0) o[i >> 1] = h;
    }
}

extern "C" void kernel_launch(void* const* d_in, const int* in_sizes, int n_in,
                              void* d_out, int out_size, void* d_ws, size_t ws_size,
                              hipStream_t stream) {
    const float* z   = (const float*)d_in[0];
    float*       out = (float*)d_out;
    film_growth_kernel<<<dim3((BATCH + 63) / 64), dim3(64), 0, stream>>>(z, out);
}